// Round 3
// baseline (61.307 us; speedup 1.0000x reference)
//
#include <hip/hip_runtime.h>

#define CUTN 128
#define CUT_SIZE 224
#define IMG_H 1024
#define IMG_W 1024
#define PAD 256          // IMG_H / 4
#define SIDE 1536        // IMG_H + 2*PAD

// One block per (cut, output row y). 256 threads: all stage, 224 compute.
__global__ __launch_bounds__(256) void make_cutouts_kernel(
    const float* __restrict__ img,      // (3, 1024, 1024)
    const int* __restrict__ sizes_y,
    const int* __restrict__ sizes_x,
    const int* __restrict__ offs_y,
    const int* __restrict__ offs_x,
    float* __restrict__ out)            // (128, 3, 224, 224)
{
    __shared__ float lds[3][2][IMG_W];  // 24 KB: [channel][row-tap][x - xv_min]

    const int bid = blockIdx.x;
    const int cut = bid / CUT_SIZE;     // uniform per block
    const int y   = bid - cut * CUT_SIZE;
    const int tid = threadIdx.x;

    const float syf = (float)sizes_y[cut];
    const float sxf = (float)sizes_x[cut];
    const float oyf = (float)offs_y[cut];
    const float oxf = (float)offs_x[cut];

    // ---- vertical coords (uniform per block) ----
    const float gy = ((float)y + 0.5f) / (float)CUT_SIZE;
    const float ys = fminf(fmaxf(oyf + gy * syf - 0.5f, 0.0f), (float)(SIDE - 1));
    const int   y0 = (int)floorf(ys);
    const float wy = ys - (float)y0;
    const int  yy0 = y0 - PAD;
    const int  yy1 = min(y0 + 1, SIDE - 1) - PAD;
    const bool vy0 = (unsigned)yy0 < (unsigned)IMG_H;
    const bool vy1 = (unsigned)yy1 < (unsigned)IMG_H;

    // ---- horizontal source range (uniform per block) ----
    const float xs_min = fminf(fmaxf(oxf + (0.5f / (float)CUT_SIZE) * sxf - 0.5f, 0.0f), (float)(SIDE - 1));
    const float xs_max = fminf(fmaxf(oxf + (223.5f / (float)CUT_SIZE) * sxf - 0.5f, 0.0f), (float)(SIDE - 1));
    const int x0_min = (int)floorf(xs_min);
    const int x0_max = (int)floorf(xs_max);
    const int xv_min = max(x0_min - PAD, 0);                    // first valid image x staged
    const int xv_max = min(x0_max + 1 - PAD, IMG_W - 1);        // last valid image x staged
    const int n_valid = xv_max - xv_min + 1;                    // may be <= 0 (fully in pad)

    // ---- stage: coalesced dwordx4 copy of each needed (channel, row) span ----
    if (n_valid > 0) {
        const int i4 = tid * 4;                                 // n_valid <= 1024 = 256*4
        #pragma unroll
        for (int c = 0; c < 3; ++c) {
            const float* plane = img + (size_t)c * (IMG_H * IMG_W);
            #pragma unroll
            for (int t = 0; t < 2; ++t) {
                const int  row = (t == 0) ? yy0 : yy1;
                const bool vr  = (t == 0) ? vy0 : vy1;
                if (vr && i4 < n_valid) {
                    const float* src = plane + (size_t)row * IMG_W + xv_min;
                    if (i4 + 4 <= n_valid) {
                        float4 v; __builtin_memcpy(&v, src + i4, 16);
                        lds[c][t][i4 + 0] = v.x;
                        lds[c][t][i4 + 1] = v.y;
                        lds[c][t][i4 + 2] = v.z;
                        lds[c][t][i4 + 3] = v.w;
                    } else {
                        for (int k = i4; k < n_valid; ++k) lds[c][t][k] = src[k];
                    }
                }
            }
        }
    }
    __syncthreads();

    // ---- compute: 224 threads, one output pixel per thread per channel ----
    if (tid < CUT_SIZE) {
        const int x = tid;
        const float gx  = ((float)x + 0.5f) / (float)CUT_SIZE;
        const float xsf = fminf(fmaxf(oxf + gx * sxf - 0.5f, 0.0f), (float)(SIDE - 1));
        const int   x0  = (int)floorf(xsf);
        const float wx  = xsf - (float)x0;
        const int  xx0  = x0 - PAD;
        const int  xx1  = min(x0 + 1, SIDE - 1) - PAD;
        const bool vx0  = (unsigned)xx0 < (unsigned)IMG_W;
        const bool vx1  = (unsigned)xx1 < (unsigned)IMG_W;
        const int k0 = xx0 - xv_min;    // in-bounds whenever vx0 (see range derivation)
        const int k1 = xx1 - xv_min;

        const float w00 = (1.0f - wy) * (1.0f - wx);
        const float w01 = (1.0f - wy) * wx;
        const float w10 = wy * (1.0f - wx);
        const float w11 = wy * wx;

        #pragma unroll
        for (int c = 0; c < 3; ++c) {
            const float p00 = (vy0 && vx0) ? lds[c][0][k0] : 0.0f;
            const float p01 = (vy0 && vx1) ? lds[c][0][k1] : 0.0f;
            const float p10 = (vy1 && vx0) ? lds[c][1][k0] : 0.0f;
            const float p11 = (vy1 && vx1) ? lds[c][1][k1] : 0.0f;
            const float v = p00 * w00 + p01 * w01 + p10 * w10 + p11 * w11;
            __builtin_nontemporal_store(
                v, &out[(((size_t)cut * 3 + c) * CUT_SIZE + y) * CUT_SIZE + x]);
        }
    }
}

extern "C" void kernel_launch(void* const* d_in, const int* in_sizes, int n_in,
                              void* d_out, int out_size, void* d_ws, size_t ws_size,
                              hipStream_t stream) {
    const float* img     = (const float*)d_in[0];
    const int*   sizes_y = (const int*)d_in[1];
    const int*   sizes_x = (const int*)d_in[2];
    const int*   offs_y  = (const int*)d_in[3];
    const int*   offs_x  = (const int*)d_in[4];
    float* out = (float*)d_out;

    const int grid = CUTN * CUT_SIZE;   // 28,672 blocks of 256
    make_cutouts_kernel<<<grid, 256, 0, stream>>>(img, sizes_y, sizes_x,
                                                  offs_y, offs_x, out);
}